// Round 1
// baseline (407.376 us; speedup 1.0000x reference)
//
#include <hip/hip_runtime.h>
#include <math.h>

// DDSP-style Generator for MI355X.
// Structure:
//   k_lin     : x @ lin_w -> (B,128,4)
//   k_upconv  : [fft-upsample 2x as exact (2n x n) matrix] + conv3 + leaky, 4 stages, then fin conv
//   k_dc      : DC of each noise window (rfft coeff 0) -- noise model keeps ONLY DC (mask_after=1)
//   k_heads   : instance-norm + 1x1-conv chains -> amp, freq, per-frame noise constants
//   k_prefix  : per-(b,osc) segment-start phases P0[65] in fp64 (cumsum closed form per linear segment)
//   k_harm    : 67M sin evals; phase = P0 + pi*(c1*f_lo + c2*df) closed form, fp64 mod-2pi, v_sin_f32
// All dot products accumulate in fp64 (freq path has ~5e4 amplification into tail phase).

static constexpr double PI_D    = 3.14159265358979323846;
static constexpr double INV2PI  = 0.15915494309189533576588;
static constexpr double LOWEST_D = 40.0 / 11025.0;

#define NB    32
#define NLAT  128
#define NCUP  128
#define NMID  64
#define NOSC_ 128
#define NFRM  64
#define NSMP  16384

// ---------------- k_lin : (B,128) @ (128,512) + b -> (B,128,4) ----------------
__global__ __launch_bounds__(128) void k_lin(const float* __restrict__ x,
                                             const float* __restrict__ lw,
                                             const float* __restrict__ lb,
                                             float* __restrict__ out) {
  int b = blockIdx.x;
  int c = threadIdx.x;   // 0..127 output channel
  __shared__ float xs[NLAT];
  xs[c] = x[b*NLAT + c];
  __syncthreads();
  double a0=0, a1=0, a2=0, a3=0;
  for (int l = 0; l < NLAT; ++l) {
    double xv = (double)xs[l];
    float4 wv = *reinterpret_cast<const float4*>(lw + (size_t)l*512 + c*4);
    a0 += xv*(double)wv.x; a1 += xv*(double)wv.y;
    a2 += xv*(double)wv.z; a3 += xv*(double)wv.w;
  }
  float4 bv = *reinterpret_cast<const float4*>(lb + c*4);
  float4 o;
  o.x = (float)(a0 + (double)bv.x);
  o.y = (float)(a1 + (double)bv.y);
  o.z = (float)(a2 + (double)bv.z);
  o.w = (float)(a3 + (double)bv.w);
  *reinterpret_cast<float4*>(out + (size_t)b*512 + c*4) = o;
}

// ------------- k_upconv : [upsample 2x] + conv3('same') + bias [+ leaky] -------------
// Band-limited 2x upsample y = K x with K[m][j] = (1/n)[1 + 2*sum_{k=1}^{n/2-1} cos(pi k (m-2j)/n)
//                                                   + 2*cos(pi m/2)*(-1)^j]   (verified vs rfft/pad/irfft)
template<int NIN, int OCTOT, bool UPS, bool LEAKY>
__global__ __launch_bounds__(256) void k_upconv(const float* __restrict__ in,
                                                const float* __restrict__ w,
                                                const float* __restrict__ bias,
                                                float* __restrict__ out) {
  constexpr int T   = UPS ? 2*NIN : NIN;
  constexpr int OCB = 32;            // output channels per block
  constexpr int TPO = 256/OCB;       // 8 threads per output channel
  constexpr int TT  = T/TPO;         // time points per thread
  static_assert(T % TPO == 0, "bad tiling");

  int b = blockIdx.x, g = blockIdx.y;
  int o0 = g*OCB;
  int tid = threadIdx.x;

  __shared__ float  u[NCUP * T];                 // (possibly upsampled) input, all 128 channels
  __shared__ float  wl[OCB * 385];               // weights, padded stride (385%32==1 -> no LDS conflicts)
  __shared__ float  cur[UPS ? NCUP*NIN : 1];
  __shared__ double Kt[UPS ? NIN*2*NIN : 1];     // transposed: Kt[j][m]
  __shared__ double ctab[UPS ? 2*NIN : 1];

  for (int i = tid; i < OCB*384; i += 256) {
    int oi = i/384, r = i - oi*384;
    wl[oi*385 + r] = w[(size_t)(o0+oi)*384 + r];
  }
  if (UPS) {
    for (int i = tid; i < NCUP*NIN; i += 256) cur[i] = in[(size_t)b*NCUP*NIN + i];
    for (int d = tid; d < 2*NIN; d += 256) ctab[d] = cos(PI_D * (double)d / (double)NIN);
    __syncthreads();
    for (int i = tid; i < NIN*2*NIN; i += 256) {
      int j = i / (2*NIN), m = i - j*(2*NIN);
      int dm = m - 2*j;
      double s = 1.0;
      #pragma unroll
      for (int k = 1; k <= NIN/2 - 1; ++k) {
        int dd = (k*dm) & (2*NIN - 1);           // mod 2n (power of 2)
        s += 2.0 * ctab[dd];
      }
      double cm2 = (m & 1) ? 0.0 : ((m & 2) ? -1.0 : 1.0);  // cos(pi m / 2)
      s += 2.0 * cm2 * ((j & 1) ? -1.0 : 1.0);
      Kt[j*(2*NIN) + m] = s / (double)NIN;
    }
    __syncthreads();
    for (int i = tid; i < NCUP*2*NIN; i += 256) {
      int c = i / (2*NIN), m = i - c*(2*NIN);
      double a = 0.0;
      for (int j = 0; j < NIN; ++j) a += Kt[j*(2*NIN) + m] * (double)cur[c*NIN + j];
      u[c*T + m] = (float)a;
    }
    __syncthreads();
  } else {
    for (int i = tid; i < NCUP*T; i += 256) u[i] = in[(size_t)b*NCUP*T + i];
    __syncthreads();
  }

  int oi = tid / TPO;
  int tq = tid - oi*TPO;
  double acc[TT];
  #pragma unroll
  for (int t = 0; t < TT; ++t) acc[t] = 0.0;
  int tbase = tq*TT - 1;
  for (int c = 0; c < NCUP; ++c) {
    float w0 = wl[oi*385 + c*3 + 0];
    float w1 = wl[oi*385 + c*3 + 1];
    float w2 = wl[oi*385 + c*3 + 2];
    float xv[TT+2];
    #pragma unroll
    for (int i = 0; i < TT+2; ++i) {
      int t = tbase + i;
      xv[i] = (t >= 0 && t < T) ? u[c*T + t] : 0.f;   // zero pad
    }
    #pragma unroll
    for (int t = 0; t < TT; ++t)
      acc[t] += (double)w0*(double)xv[t] + (double)w1*(double)xv[t+1] + (double)w2*(double)xv[t+2];
  }
  float bo = bias[o0 + oi];
  #pragma unroll
  for (int t = 0; t < TT; ++t) {
    float v = (float)(acc[t] + (double)bo);
    if (LEAKY) v = (v > 0.f) ? v : 0.2f*v;
    out[(size_t)b*OCTOT*T + (size_t)(o0+oi)*T + tq*TT + t] = v;
  }
}

// ------------- k_dc : DC (sum) of each 512-sample noise window -------------
__global__ __launch_bounds__(64) void k_dc(const float* __restrict__ noise, float* __restrict__ dc) {
  int f = blockIdx.x, b = blockIdx.y;
  int lane = threadIdx.x;
  const float* p = noise + ((size_t)b*NFRM + f)*512;
  double a = 0.0;
  for (int i = lane; i < 512; i += 64) a += (double)p[i];
  for (int off = 32; off > 0; off >>= 1) a += __shfl_down(a, off);
  if (lane == 0) dc[b*NFRM + f] = (float)a;
}

// ------------- k_heads : instance norm + 1x1 chains -> amp, freq, noise constants -------------
__global__ __launch_bounds__(256) void k_heads(const float* __restrict__ hfin,
    const float* __restrict__ hw1, const float* __restrict__ hb1,
    const float* __restrict__ hw2, const float* __restrict__ hb2,
    const float* __restrict__ tw1, const float* __restrict__ tb1,
    const float* __restrict__ tw2, const float* __restrict__ tb2,
    const float* __restrict__ amp_w, const float* __restrict__ amp_b,
    const float* __restrict__ freq_w, const float* __restrict__ freq_b,
    const float* __restrict__ nm_w1, const float* __restrict__ nm_b1,
    const float* __restrict__ nm_w2, const float* __restrict__ nm_b2,
    const float* __restrict__ dc, float* __restrict__ ampg,
    float* __restrict__ freqg, float* __restrict__ ncontrib) {
  int b = blockIdx.x, tid = threadIdx.x;
  __shared__ float hbuf[NMID*NMID], t1[NMID*NMID], hh[NMID*NMID], nb[NMID*NMID];
  __shared__ float meanv[NMID], scalev[NMID];
  __shared__ double veff[NMID];

  for (int i = tid; i < NMID*NMID; i += 256) hbuf[i] = hfin[(size_t)b*NMID*NMID + i];
  if (tid < NMID) {   // veff[m] = sum_c nm_w2[0,c] * nm_w1[c,m]  (only spec row 0 survives the mask)
    double a = 0.0;
    for (int c = 0; c < NCUP; ++c) a += (double)nm_w2[c] * (double)nm_w1[c*NMID + tid];
    veff[tid] = a;
  }
  __syncthreads();
  if (tid < NMID) {   // instance-norm stats per channel over T=64
    double s = 0.0;
    for (int t = 0; t < NMID; ++t) s += (double)hbuf[tid*NMID + t];
    double m = s * (1.0/NMID);
    double s2 = 0.0;
    for (int t = 0; t < NMID; ++t) { double d = (double)hbuf[tid*NMID + t] - m; s2 += d*d; }
    meanv[tid] = (float)m;
    scalev[tid] = (float)(1.0 / sqrt(s2 * (1.0/NMID) + 1e-5));
  }
  __syncthreads();
  for (int i = tid; i < NMID*NMID; i += 256) {
    int c = i >> 6;
    hbuf[i] = (hbuf[i] - meanv[c]) * scalev[c];
  }
  __syncthreads();
  for (int i = tid; i < NMID*NMID; i += 256) {          // t1 = leaky(hw1 @ h + hb1)
    int o = i >> 6, t = i & 63;
    double a = (double)hb1[o];
    for (int c = 0; c < NMID; ++c) a += (double)hw1[o*NMID + c] * (double)hbuf[c*NMID + t];
    float v = (float)a;
    t1[i] = (v > 0.f) ? v : 0.2f*v;
  }
  __syncthreads();
  for (int i = tid; i < NMID*NMID; i += 256) {          // hh = hw2 @ t1 + hb2
    int o = i >> 6, t = i & 63;
    double a = (double)hb2[o];
    for (int c = 0; c < NMID; ++c) a += (double)hw2[o*NMID + c] * (double)t1[c*NMID + t];
    hh[i] = (float)a;
  }
  __syncthreads();
  for (int i = tid; i < NMID*NMID; i += 256) {          // t1 = leaky(tw1 @ h + tb1)
    int o = i >> 6, t = i & 63;
    double a = (double)tb1[o];
    for (int c = 0; c < NMID; ++c) a += (double)tw1[o*NMID + c] * (double)hbuf[c*NMID + t];
    float v = (float)a;
    t1[i] = (v > 0.f) ? v : 0.2f*v;
  }
  __syncthreads();
  for (int i = tid; i < NMID*NMID; i += 256) {          // nb = tw2 @ t1 + tb2
    int o = i >> 6, t = i & 63;
    double a = (double)tb2[o];
    for (int c = 0; c < NMID; ++c) a += (double)tw2[o*NMID + c] * (double)t1[c*NMID + t];
    nb[i] = (float)a;
  }
  __syncthreads();
  for (int i = tid; i < NOSC_*NMID; i += 256) {         // amp / freq heads
    int o = i >> 6, t = i & 63;
    double za = (double)amp_b[o], zf = (double)freq_b[o];
    for (int c = 0; c < NMID; ++c) {
      double hv = (double)hh[c*NMID + t];
      za += (double)amp_w[o*NMID + c] * hv;
      zf += (double)freq_w[o*NMID + c] * hv;
    }
    ampg[(size_t)b*NOSC_*NMID + i] = fabsf((float)za);
    double sg = 1.0 / (1.0 + exp(-zf));
    freqg[(size_t)b*NOSC_*NMID + i] = (float)(LOWEST_D + sg*sg*(1.0 - LOWEST_D));
  }
  if (tid < NFRM) {                                     // per-frame noise constant (DC-only filter)
    int f = tid;
    double beff = (double)nm_b2[0];
    for (int c = 0; c < NCUP; ++c) beff += (double)nm_w2[c] * (double)nm_b1[c];
    double s0 = beff;
    for (int m = 0; m < NMID; ++m) s0 += veff[m] * (double)nb[m*NMID + f];
    ncontrib[b*NFRM + f] = (float)((double)dc[b*NFRM + f] * s0 * (1.0/512.0));
  }
}

// ------------- k_prefix : per-(b,osc) segment-start phases (fp64) + segment tables -------------
// Segments of the 64->16384 linterp: seg0 = [0,128) const f[0]; seg j(1..63) = [256j-128,256j+128)
// linear f[j-1]->f[j] with w = 1/512 + i/256; seg64 = [16256,16384) const f[63].
// Segment sums: 128*f0 ; 128*(f[j-1]+f[j]) ; so P0 is a cheap 64-step fp64 scan.
__global__ __launch_bounds__(256) void k_prefix(const float* __restrict__ freqg,
                                                const float* __restrict__ ampg,
                                                double* __restrict__ P0g,
                                                float4* __restrict__ segT) {
  int idx = blockIdx.x*blockDim.x + threadIdx.x;   // 0..4095 = b*128+osc
  int b = idx >> 7, osc = idx & 127;
  const float* F = freqg + (size_t)b*NOSC_*NFRM + osc*NFRM;
  const float* A = ampg  + (size_t)b*NOSC_*NFRM + osc*NFRM;
  P0g[0*4096 + idx] = 0.0;
  segT[0*4096 + idx] = make_float4(F[0], 0.f, A[0], 0.f);
  double p = PI_D * 128.0 * (double)F[0];
  for (int j = 1; j <= 63; ++j) {
    P0g[j*4096 + idx] = p;
    float fl = F[j-1], fh = F[j], al = A[j-1], ah = A[j];
    segT[j*4096 + idx] = make_float4(fl, fh - fl, al, ah - al);
    p += PI_D * 128.0 * ((double)fl + (double)fh);
  }
  P0g[64*4096 + idx] = p;
  segT[64*4096 + idx] = make_float4(F[63], 0.f, A[63], 0.f);
}

// ------------- k_harm : the heavy kernel. block = (q,b): 256 samples, 128 oscillators -------------
// Block covers samples [256q, 256q+256): first half lies in segment q, second half in segment q+1.
// phase(s) = P0 + pi*((r+1)*f_lo + df*((r+1)*w0 + r(r+1)/512)), exact fp64, reduced mod 2pi -> v_sin_f32.
__global__ __launch_bounds__(256) void k_harm(const double* __restrict__ P0g,
                                              const float4* __restrict__ segT,
                                              const float* __restrict__ nc,
                                              float* __restrict__ outp) {
  int q = blockIdx.x;        // 0..63
  int b = blockIdx.y;
  int tid = threadIdx.x;
  __shared__ double P0s[256];     // [half][osc]
  __shared__ float4 segs[256];
  int half = tid >> 7;
  int osc  = tid & 127;
  {
    int j = q + half;
    P0s[tid]  = P0g[(size_t)j*4096 + b*128 + osc];
    segs[tid] = segT[(size_t)j*4096 + b*128 + osc];
  }
  __syncthreads();

  int j = q + half;
  int s = q*256 + tid;
  int r = (j == 0) ? s : (s - (256*j - 128));
  float w0 = (j == 0 || j == 64) ? 0.f : (1.f/512.f);
  double rp = (double)(r + 1);
  double c1 = rp * PI_D;
  double c2 = (rp*(double)w0 + (double)r*rp*(1.0/512.0)) * PI_D;
  float wr = w0 + (float)r*(1.f/256.f);

  const double* P0p = P0s + half*128;
  const float4* sp  = segs + half*128;
  float acc = 0.f;
  #pragma unroll 4
  for (int o = 0; o < 128; ++o) {
    float4 sg = sp[o];                 // {f_lo, df, a_lo, da} -- wave-uniform LDS broadcast
    double ph = P0p[o] + c1*(double)sg.x + c2*(double)sg.y;
    double rev = ph * INV2PI;
    rev -= floor(rev);                 // fractional revolutions, exact to ~5e-13
    float sv = __builtin_amdgcn_sinf((float)rev);   // v_sin_f32: sin(2*pi*x)
    float am = sg.z + sg.w*wr;
    acc = fmaf(sv, am, acc);
  }
  // noise: frame q covers [256q,256q+512), frame q-1 covers [256q-256,256q+256) -> both span the block
  float ns = nc[b*NFRM + q] + ((q > 0) ? nc[b*NFRM + q - 1] : 0.f);
  outp[(size_t)b*NSMP + s] = acc + ns;
}

// ---------------------------------------------------------------------------
extern "C" void kernel_launch(void* const* d_in, const int* in_sizes, int n_in,
                              void* d_out, int out_size, void* d_ws, size_t ws_size,
                              hipStream_t stream) {
  (void)in_sizes; (void)n_in; (void)out_size; (void)ws_size;
  const float* x      = (const float*)d_in[0];
  const float* lin_w  = (const float*)d_in[1];
  const float* lin_b  = (const float*)d_in[2];
  const float* up_w0  = (const float*)d_in[3];
  const float* up_b0  = (const float*)d_in[4];
  const float* up_w1  = (const float*)d_in[5];
  const float* up_b1  = (const float*)d_in[6];
  const float* up_w2  = (const float*)d_in[7];
  const float* up_b2  = (const float*)d_in[8];
  const float* up_w3  = (const float*)d_in[9];
  const float* up_b3  = (const float*)d_in[10];
  const float* fin_w  = (const float*)d_in[11];
  const float* fin_b  = (const float*)d_in[12];
  const float* hw1    = (const float*)d_in[13];
  const float* hb1    = (const float*)d_in[14];
  const float* hw2    = (const float*)d_in[15];
  const float* hb2    = (const float*)d_in[16];
  const float* tw1    = (const float*)d_in[17];
  const float* tb1    = (const float*)d_in[18];
  const float* tw2    = (const float*)d_in[19];
  const float* tb2    = (const float*)d_in[20];
  const float* amp_w  = (const float*)d_in[21];
  const float* amp_b  = (const float*)d_in[22];
  const float* freq_w = (const float*)d_in[23];
  const float* freq_b = (const float*)d_in[24];
  const float* nm_w1  = (const float*)d_in[25];
  const float* nm_b1  = (const float*)d_in[26];
  const float* nm_w2  = (const float*)d_in[27];
  const float* nm_b2  = (const float*)d_in[28];
  const float* noise  = (const float*)d_in[29];

  float* ws = (float*)d_ws;
  float* buf0  = ws;                       // 262144 floats
  float* buf1  = ws + 262144;              // 262144
  float* hfin  = ws + 524288;              // 131072
  float* ampg  = ws + 655360;              // 262144
  float* freqg = ws + 917504;              // 262144
  float* dc    = ws + 1179648;             // 2048
  float* ncon  = ws + 1181696;             // 2048
  double* P0g  = (double*)(ws + 1183744);  // 65*4096 doubles (byte offset % 8 == 0)
  float4* segT = (float4*)(ws + 1716224);  // 65*4096 float4  (byte offset % 16 == 0)

  k_lin<<<NB, 128, 0, stream>>>(x, lin_w, lin_b, buf0);
  k_upconv< 4, 128, true,  true ><<<dim3(NB,4), 256, 0, stream>>>(buf0, up_w0, up_b0, buf1);
  k_upconv< 8, 128, true,  true ><<<dim3(NB,4), 256, 0, stream>>>(buf1, up_w1, up_b1, buf0);
  k_upconv<16, 128, true,  true ><<<dim3(NB,4), 256, 0, stream>>>(buf0, up_w2, up_b2, buf1);
  k_upconv<32, 128, true,  true ><<<dim3(NB,4), 256, 0, stream>>>(buf1, up_w3, up_b3, buf0);
  k_upconv<64,  64, false, false><<<dim3(NB,2), 256, 0, stream>>>(buf0, fin_w, fin_b, hfin);
  k_dc<<<dim3(NFRM, NB), 64, 0, stream>>>(noise, dc);
  k_heads<<<NB, 256, 0, stream>>>(hfin, hw1, hb1, hw2, hb2, tw1, tb1, tw2, tb2,
                                  amp_w, amp_b, freq_w, freq_b,
                                  nm_w1, nm_b1, nm_w2, nm_b2,
                                  dc, ampg, freqg, ncon);
  k_prefix<<<16, 256, 0, stream>>>(freqg, ampg, P0g, segT);
  k_harm<<<dim3(64, NB), 256, 0, stream>>>(P0g, segT, ncon, (float*)d_out);
}

// Round 3
// 246.225 us; speedup vs baseline: 1.6545x; 1.6545x over previous
//
#include <hip/hip_runtime.h>
#include <math.h>

// DDSP-style Generator for MI355X.
// R1: split the latency-bound k_heads (230us, 32 blocks, 1.4% occupancy) into
//     5 massively-parallel kernels (k_norm/k_mm1/k_mm2/k_af/k_ncon).
// R2: resubmit (infra failure, no data).
// Structure:
//   k_lin     : x @ lin_w -> (B,128,4)
//   k_upconv  : [fft-upsample 2x as exact (2n x n) matrix] + conv3 + leaky, 4 stages, then fin conv
//   k_dc      : DC of each noise window (rfft coeff 0) -- noise model keeps ONLY DC (mask_after=1)
//   k_norm    : instance-norm, one wave per (b,channel)
//   k_mm1/2   : 1x1-conv chains, one thread per output element
//   k_af      : amp/freq heads fused
//   k_ncon    : per-frame noise constants (DC-only filter)
//   k_prefix  : per-(b,osc) segment-start phases P0[65] in fp64 (cumsum closed form per linear segment)
//   k_harm    : 67M sin evals; phase = P0 + pi*(c1*f_lo + c2*df) closed form, fp64 mod-2pi, v_sin_f32
// All dot products accumulate in fp64 (freq path has ~5e4 amplification into tail phase).

static constexpr double PI_D    = 3.14159265358979323846;
static constexpr double INV2PI  = 0.15915494309189533576588;
static constexpr double LOWEST_D = 40.0 / 11025.0;

#define NB    32
#define NLAT  128
#define NCUP  128
#define NMID  64
#define NOSC_ 128
#define NFRM  64
#define NSMP  16384

// ---------------- k_lin : (B,128) @ (128,512) + b -> (B,128,4) ----------------
__global__ __launch_bounds__(128) void k_lin(const float* __restrict__ x,
                                             const float* __restrict__ lw,
                                             const float* __restrict__ lb,
                                             float* __restrict__ out) {
  int b = blockIdx.x;
  int c = threadIdx.x;   // 0..127 output channel
  __shared__ float xs[NLAT];
  xs[c] = x[b*NLAT + c];
  __syncthreads();
  double a0=0, a1=0, a2=0, a3=0;
  for (int l = 0; l < NLAT; ++l) {
    double xv = (double)xs[l];
    float4 wv = *reinterpret_cast<const float4*>(lw + (size_t)l*512 + c*4);
    a0 += xv*(double)wv.x; a1 += xv*(double)wv.y;
    a2 += xv*(double)wv.z; a3 += xv*(double)wv.w;
  }
  float4 bv = *reinterpret_cast<const float4*>(lb + c*4);
  float4 o;
  o.x = (float)(a0 + (double)bv.x);
  o.y = (float)(a1 + (double)bv.y);
  o.z = (float)(a2 + (double)bv.z);
  o.w = (float)(a3 + (double)bv.w);
  *reinterpret_cast<float4*>(out + (size_t)b*512 + c*4) = o;
}

// ------------- k_upconv : [upsample 2x] + conv3('same') + bias [+ leaky] -------------
// Band-limited 2x upsample y = K x with K[m][j] = (1/n)[1 + 2*sum_{k=1}^{n/2-1} cos(pi k (m-2j)/n)
//                                                   + 2*cos(pi m/2)*(-1)^j]   (verified vs rfft/pad/irfft)
template<int NIN, int OCTOT, bool UPS, bool LEAKY>
__global__ __launch_bounds__(256) void k_upconv(const float* __restrict__ in,
                                                const float* __restrict__ w,
                                                const float* __restrict__ bias,
                                                float* __restrict__ out) {
  constexpr int T   = UPS ? 2*NIN : NIN;
  constexpr int OCB = 32;            // output channels per block
  constexpr int TPO = 256/OCB;       // 8 threads per output channel
  constexpr int TT  = T/TPO;         // time points per thread
  static_assert(T % TPO == 0, "bad tiling");

  int b = blockIdx.x, g = blockIdx.y;
  int o0 = g*OCB;
  int tid = threadIdx.x;

  __shared__ float  u[NCUP * T];                 // (possibly upsampled) input, all 128 channels
  __shared__ float  wl[OCB * 385];               // weights, padded stride (385%32==1 -> no LDS conflicts)
  __shared__ float  cur[UPS ? NCUP*NIN : 1];
  __shared__ double Kt[UPS ? NIN*2*NIN : 1];     // transposed: Kt[j][m]
  __shared__ double ctab[UPS ? 2*NIN : 1];

  for (int i = tid; i < OCB*384; i += 256) {
    int oi = i/384, r = i - oi*384;
    wl[oi*385 + r] = w[(size_t)(o0+oi)*384 + r];
  }
  if (UPS) {
    for (int i = tid; i < NCUP*NIN; i += 256) cur[i] = in[(size_t)b*NCUP*NIN + i];
    for (int d = tid; d < 2*NIN; d += 256) ctab[d] = cos(PI_D * (double)d / (double)NIN);
    __syncthreads();
    for (int i = tid; i < NIN*2*NIN; i += 256) {
      int j = i / (2*NIN), m = i - j*(2*NIN);
      int dm = m - 2*j;
      double s = 1.0;
      #pragma unroll
      for (int k = 1; k <= NIN/2 - 1; ++k) {
        int dd = (k*dm) & (2*NIN - 1);           // mod 2n (power of 2)
        s += 2.0 * ctab[dd];
      }
      double cm2 = (m & 1) ? 0.0 : ((m & 2) ? -1.0 : 1.0);  // cos(pi m / 2)
      s += 2.0 * cm2 * ((j & 1) ? -1.0 : 1.0);
      Kt[j*(2*NIN) + m] = s / (double)NIN;
    }
    __syncthreads();
    for (int i = tid; i < NCUP*2*NIN; i += 256) {
      int c = i / (2*NIN), m = i - c*(2*NIN);
      double a = 0.0;
      for (int j = 0; j < NIN; ++j) a += Kt[j*(2*NIN) + m] * (double)cur[c*NIN + j];
      u[c*T + m] = (float)a;
    }
    __syncthreads();
  } else {
    for (int i = tid; i < NCUP*T; i += 256) u[i] = in[(size_t)b*NCUP*T + i];
    __syncthreads();
  }

  int oi = tid / TPO;
  int tq = tid - oi*TPO;
  double acc[TT];
  #pragma unroll
  for (int t = 0; t < TT; ++t) acc[t] = 0.0;
  int tbase = tq*TT - 1;
  for (int c = 0; c < NCUP; ++c) {
    float w0 = wl[oi*385 + c*3 + 0];
    float w1 = wl[oi*385 + c*3 + 1];
    float w2 = wl[oi*385 + c*3 + 2];
    float xv[TT+2];
    #pragma unroll
    for (int i = 0; i < TT+2; ++i) {
      int t = tbase + i;
      xv[i] = (t >= 0 && t < T) ? u[c*T + t] : 0.f;   // zero pad
    }
    #pragma unroll
    for (int t = 0; t < TT; ++t)
      acc[t] += (double)w0*(double)xv[t] + (double)w1*(double)xv[t+1] + (double)w2*(double)xv[t+2];
  }
  float bo = bias[o0 + oi];
  #pragma unroll
  for (int t = 0; t < TT; ++t) {
    float v = (float)(acc[t] + (double)bo);
    if (LEAKY) v = (v > 0.f) ? v : 0.2f*v;
    out[(size_t)b*OCTOT*T + (size_t)(o0+oi)*T + tq*TT + t] = v;
  }
}

// ------------- k_dc : DC (sum) of each 512-sample noise window -------------
__global__ __launch_bounds__(64) void k_dc(const float* __restrict__ noise, float* __restrict__ dc) {
  int f = blockIdx.x, b = blockIdx.y;
  int lane = threadIdx.x;
  const float* p = noise + ((size_t)b*NFRM + f)*512;
  double a = 0.0;
  for (int i = lane; i < 512; i += 64) a += (double)p[i];
  for (int off = 32; off > 0; off >>= 1) a += __shfl_down(a, off);
  if (lane == 0) dc[b*NFRM + f] = (float)a;
}

// ------------- k_norm : instance norm, one wave per (b,channel) -------------
__global__ __launch_bounds__(64) void k_norm(const float* __restrict__ hfin,
                                             float* __restrict__ hnorm) {
  int bc = blockIdx.x;          // b*64 + c
  int lane = threadIdx.x;       // t
  const float* p = hfin + (size_t)bc*NMID;
  float v = p[lane];
  double s = (double)v;
  for (int off = 32; off > 0; off >>= 1) s += __shfl_down(s, off);
  double m = __shfl(s, 0) * (1.0/NMID);
  double d = (double)v - m;
  double s2 = d*d;
  for (int off = 32; off > 0; off >>= 1) s2 += __shfl_down(s2, off);
  double var = __shfl(s2, 0) * (1.0/NMID);
  float sc = (float)(1.0 / sqrt(var + 1e-5));
  hnorm[(size_t)bc*NMID + lane] = (float)d * sc;
}

// ------------- k_mm1 : t1[z] = leaky(W1[z] @ hnorm + b1[z]), z=0:h-chain z=1:t-chain -------------
__global__ __launch_bounds__(256) void k_mm1(const float* __restrict__ hnorm,
    const float* __restrict__ hw1, const float* __restrict__ hb1,
    const float* __restrict__ tw1, const float* __restrict__ tb1,
    float* __restrict__ t1buf) {
  int b = blockIdx.y, z = blockIdx.z;
  int o = blockIdx.x*4 + (threadIdx.x >> 6);     // wave-uniform -> weight loads are scalar
  int t = threadIdx.x & 63;
  const float* W = (z ? tw1 : hw1) + o*NMID;
  float bv = (z ? tb1 : hb1)[o];
  const float* X = hnorm + (size_t)b*4096 + t;
  double a0 = 0.0, a1 = 0.0;
  for (int c = 0; c < NMID; c += 2) {
    a0 += (double)W[c]   * (double)X[(size_t)c*64];
    a1 += (double)W[c+1] * (double)X[(size_t)(c+1)*64];
  }
  float v = (float)(a0 + a1 + (double)bv);
  v = (v > 0.f) ? v : 0.2f*v;
  t1buf[((size_t)b*2 + z)*4096 + o*64 + t] = v;
}

// ------------- k_mm2 : hh = hw2@t1h + hb2 (z=0); nb = tw2@t1t + tb2 (z=1) -------------
__global__ __launch_bounds__(256) void k_mm2(const float* __restrict__ t1buf,
    const float* __restrict__ hw2, const float* __restrict__ hb2,
    const float* __restrict__ tw2, const float* __restrict__ tb2,
    float* __restrict__ hh, float* __restrict__ nbuf) {
  int b = blockIdx.y, z = blockIdx.z;
  int o = blockIdx.x*4 + (threadIdx.x >> 6);
  int t = threadIdx.x & 63;
  const float* W = (z ? tw2 : hw2) + o*NMID;
  float bv = (z ? tb2 : hb2)[o];
  const float* X = t1buf + ((size_t)b*2 + z)*4096 + t;
  double a0 = 0.0, a1 = 0.0;
  for (int c = 0; c < NMID; c += 2) {
    a0 += (double)W[c]   * (double)X[(size_t)c*64];
    a1 += (double)W[c+1] * (double)X[(size_t)(c+1)*64];
  }
  float v = (float)(a0 + a1 + (double)bv);
  float* out = z ? nbuf : hh;
  out[(size_t)b*4096 + o*64 + t] = v;
}

// ------------- k_af : amp/freq heads fused -------------
__global__ __launch_bounds__(256) void k_af(const float* __restrict__ hh,
    const float* __restrict__ amp_w, const float* __restrict__ amp_b,
    const float* __restrict__ freq_w, const float* __restrict__ freq_b,
    float* __restrict__ ampg, float* __restrict__ freqg) {
  int b = blockIdx.y;
  int o = blockIdx.x*4 + (threadIdx.x >> 6);     // 0..127
  int t = threadIdx.x & 63;
  const float* X = hh + (size_t)b*4096 + t;
  const float* wa = amp_w + o*NMID;
  const float* wf = freq_w + o*NMID;
  double za = (double)amp_b[o], zf = (double)freq_b[o];
  for (int c = 0; c < NMID; ++c) {
    double hv = (double)X[(size_t)c*64];
    za += (double)wa[c]*hv;
    zf += (double)wf[c]*hv;
  }
  ampg[(size_t)b*8192 + o*64 + t] = fabsf((float)za);
  double sg = 1.0 / (1.0 + exp(-zf));
  freqg[(size_t)b*8192 + o*64 + t] = (float)(LOWEST_D + sg*sg*(1.0 - LOWEST_D));
}

// ------------- k_ncon : per-frame noise constant (DC-only filter) -------------
__global__ __launch_bounds__(64) void k_ncon(const float* __restrict__ nbuf,
    const float* __restrict__ nm_w1, const float* __restrict__ nm_b1,
    const float* __restrict__ nm_w2, const float* __restrict__ nm_b2,
    const float* __restrict__ dc, float* __restrict__ ncon) {
  int b = blockIdx.x;
  int f = threadIdx.x;            // frame
  __shared__ double veff[NMID];
  double a = 0.0;                 // veff[f] = sum_c nm_w2[0,c]*nm_w1[c,f]
  for (int c = 0; c < NCUP; ++c) a += (double)nm_w2[c] * (double)nm_w1[c*NMID + f];
  veff[f] = a;
  double beff = (double)nm_b2[0];
  for (int c = 0; c < NCUP; ++c) beff += (double)nm_w2[c] * (double)nm_b1[c];
  __syncthreads();
  double s0 = beff;
  const float* nbp = nbuf + (size_t)b*4096 + f;
  for (int m = 0; m < NMID; ++m) s0 += veff[m] * (double)nbp[(size_t)m*64];
  ncon[b*NFRM + f] = (float)((double)dc[b*NFRM + f] * s0 * (1.0/512.0));
}

// ------------- k_prefix : per-(b,osc) segment-start phases (fp64) + segment tables -------------
// Segments of the 64->16384 linterp: seg0 = [0,128) const f[0]; seg j(1..63) = [256j-128,256j+128)
// linear f[j-1]->f[j] with w = 1/512 + i/256; seg64 = [16256,16384) const f[63].
__global__ __launch_bounds__(256) void k_prefix(const float* __restrict__ freqg,
                                                const float* __restrict__ ampg,
                                                double* __restrict__ P0g,
                                                float4* __restrict__ segT) {
  int idx = blockIdx.x*blockDim.x + threadIdx.x;   // 0..4095 = b*128+osc
  int b = idx >> 7, osc = idx & 127;
  const float* F = freqg + (size_t)b*NOSC_*NFRM + osc*NFRM;
  const float* A = ampg  + (size_t)b*NOSC_*NFRM + osc*NFRM;
  P0g[0*4096 + idx] = 0.0;
  segT[0*4096 + idx] = make_float4(F[0], 0.f, A[0], 0.f);
  double p = PI_D * 128.0 * (double)F[0];
  for (int j = 1; j <= 63; ++j) {
    P0g[j*4096 + idx] = p;
    float fl = F[j-1], fh = F[j], al = A[j-1], ah = A[j];
    segT[j*4096 + idx] = make_float4(fl, fh - fl, al, ah - al);
    p += PI_D * 128.0 * ((double)fl + (double)fh);
  }
  P0g[64*4096 + idx] = p;
  segT[64*4096 + idx] = make_float4(F[63], 0.f, A[63], 0.f);
}

// ------------- k_harm : block = (q,b): 256 samples, 128 oscillators -------------
// phase(s) = P0 + pi*((r+1)*f_lo + df*((r+1)*w0 + r(r+1)/512)), exact fp64, reduced mod 2pi -> v_sin_f32.
__global__ __launch_bounds__(256) void k_harm(const double* __restrict__ P0g,
                                              const float4* __restrict__ segT,
                                              const float* __restrict__ nc,
                                              float* __restrict__ outp) {
  int q = blockIdx.x;        // 0..63
  int b = blockIdx.y;
  int tid = threadIdx.x;
  __shared__ double P0s[256];     // [half][osc]
  __shared__ float4 segs[256];
  int half = tid >> 7;
  int osc  = tid & 127;
  {
    int j = q + half;
    P0s[tid]  = P0g[(size_t)j*4096 + b*128 + osc];
    segs[tid] = segT[(size_t)j*4096 + b*128 + osc];
  }
  __syncthreads();

  int j = q + half;
  int s = q*256 + tid;
  int r = (j == 0) ? s : (s - (256*j - 128));
  float w0 = (j == 0 || j == 64) ? 0.f : (1.f/512.f);
  double rp = (double)(r + 1);
  double c1 = rp * PI_D;
  double c2 = (rp*(double)w0 + (double)r*rp*(1.0/512.0)) * PI_D;
  float wr = w0 + (float)r*(1.f/256.f);

  const double* P0p = P0s + half*128;
  const float4* sp  = segs + half*128;
  float acc = 0.f;
  #pragma unroll 4
  for (int o = 0; o < 128; ++o) {
    float4 sg = sp[o];                 // {f_lo, df, a_lo, da} -- wave-uniform LDS broadcast
    double ph = P0p[o] + c1*(double)sg.x + c2*(double)sg.y;
    double rev = ph * INV2PI;
    rev -= floor(rev);                 // fractional revolutions, exact to ~5e-13
    float sv = __builtin_amdgcn_sinf((float)rev);   // v_sin_f32: sin(2*pi*x)
    float am = sg.z + sg.w*wr;
    acc = fmaf(sv, am, acc);
  }
  float ns = nc[b*NFRM + q] + ((q > 0) ? nc[b*NFRM + q - 1] : 0.f);
  outp[(size_t)b*NSMP + s] = acc + ns;
}

// ---------------------------------------------------------------------------
extern "C" void kernel_launch(void* const* d_in, const int* in_sizes, int n_in,
                              void* d_out, int out_size, void* d_ws, size_t ws_size,
                              hipStream_t stream) {
  (void)in_sizes; (void)n_in; (void)out_size; (void)ws_size;
  const float* x      = (const float*)d_in[0];
  const float* lin_w  = (const float*)d_in[1];
  const float* lin_b  = (const float*)d_in[2];
  const float* up_w0  = (const float*)d_in[3];
  const float* up_b0  = (const float*)d_in[4];
  const float* up_w1  = (const float*)d_in[5];
  const float* up_b1  = (const float*)d_in[6];
  const float* up_w2  = (const float*)d_in[7];
  const float* up_b2  = (const float*)d_in[8];
  const float* up_w3  = (const float*)d_in[9];
  const float* up_b3  = (const float*)d_in[10];
  const float* fin_w  = (const float*)d_in[11];
  const float* fin_b  = (const float*)d_in[12];
  const float* hw1    = (const float*)d_in[13];
  const float* hb1    = (const float*)d_in[14];
  const float* hw2    = (const float*)d_in[15];
  const float* hb2    = (const float*)d_in[16];
  const float* tw1    = (const float*)d_in[17];
  const float* tb1    = (const float*)d_in[18];
  const float* tw2    = (const float*)d_in[19];
  const float* tb2    = (const float*)d_in[20];
  const float* amp_w  = (const float*)d_in[21];
  const float* amp_b  = (const float*)d_in[22];
  const float* freq_w = (const float*)d_in[23];
  const float* freq_b = (const float*)d_in[24];
  const float* nm_w1  = (const float*)d_in[25];
  const float* nm_b1  = (const float*)d_in[26];
  const float* nm_w2  = (const float*)d_in[27];
  const float* nm_b2  = (const float*)d_in[28];
  const float* noise  = (const float*)d_in[29];

  float* ws = (float*)d_ws;
  float* buf0  = ws;                       // 262144 floats
  float* buf1  = ws + 262144;              // 262144
  float* hfin  = ws + 524288;              // 131072 (dead after k_norm -> reused for nb)
  float* ampg  = ws + 655360;              // 262144
  float* freqg = ws + 917504;              // 262144
  float* dc    = ws + 1179648;             // 2048
  float* ncon  = ws + 1181696;             // 2048
  double* P0g  = (double*)(ws + 1183744);  // 65*4096 doubles
  float4* segT = (float4*)(ws + 1716224);  // 65*4096 float4

  // post-upconv reuse (regions dead by the time they're written):
  float* hnorm = buf1;                     // 131072 (buf1 free after stage 4)
  float* hh    = buf1 + 131072;            // 131072
  float* t1buf = buf0;                     // 262144 (buf0 free after fin conv)
  float* nbuf  = hfin;                     // 131072 (hfin free after k_norm)

  k_lin<<<NB, 128, 0, stream>>>(x, lin_w, lin_b, buf0);
  k_upconv< 4, 128, true,  true ><<<dim3(NB,4), 256, 0, stream>>>(buf0, up_w0, up_b0, buf1);
  k_upconv< 8, 128, true,  true ><<<dim3(NB,4), 256, 0, stream>>>(buf1, up_w1, up_b1, buf0);
  k_upconv<16, 128, true,  true ><<<dim3(NB,4), 256, 0, stream>>>(buf0, up_w2, up_b2, buf1);
  k_upconv<32, 128, true,  true ><<<dim3(NB,4), 256, 0, stream>>>(buf1, up_w3, up_b3, buf0);
  k_upconv<64,  64, false, false><<<dim3(NB,2), 256, 0, stream>>>(buf0, fin_w, fin_b, hfin);
  k_dc<<<dim3(NFRM, NB), 64, 0, stream>>>(noise, dc);
  k_norm<<<NB*NMID, 64, 0, stream>>>(hfin, hnorm);
  k_mm1<<<dim3(16, NB, 2), 256, 0, stream>>>(hnorm, hw1, hb1, tw1, tb1, t1buf);
  k_mm2<<<dim3(16, NB, 2), 256, 0, stream>>>(t1buf, hw2, hb2, tw2, tb2, hh, nbuf);
  k_af<<<dim3(32, NB), 256, 0, stream>>>(hh, amp_w, amp_b, freq_w, freq_b, ampg, freqg);
  k_ncon<<<NB, 64, 0, stream>>>(nbuf, nm_w1, nm_b1, nm_w2, nm_b2, dc, ncon);
  k_prefix<<<16, 256, 0, stream>>>(freqg, ampg, P0g, segT);
  k_harm<<<dim3(64, NB), 256, 0, stream>>>(P0g, segT, ncon, (float*)d_out);
}

// Round 5
// 228.620 us; speedup vs baseline: 1.7819x; 1.0770x over previous
//
#include <hip/hip_runtime.h>
#include <math.h>

// DDSP-style Generator for MI355X.
// R1: split latency-bound k_heads (230us, 1.4% occ) into 5 parallel kernels. 407->246us.
// R3: k_upconv dominates (53us @ NIN=32; 1 block/CU, 113KB LDS, 1.5M bank conflicts).
//     Split each stage into k_kmat (once) + k_ups (thread/elem) + k_conv (LDS-tiled,
//     256/T channels per block). Also fold 1/(2pi) into phase accumulation (rev units)
//     to drop one fp64 mul per k_harm inner iteration.
// R4: resubmit (infra failure, no data).
// All dot products accumulate in fp64 (freq path has ~5e4 amplification into tail phase).

static constexpr double PI_D    = 3.14159265358979323846;
static constexpr double LOWEST_D = 40.0 / 11025.0;

#define NB    32
#define NLAT  128
#define NCUP  128
#define NMID  64
#define NOSC_ 128
#define NFRM  64
#define NSMP  16384

// ---------------- k_lin : (B,128) @ (128,512) + b -> (B,128,4) ----------------
__global__ __launch_bounds__(128) void k_lin(const float* __restrict__ x,
                                             const float* __restrict__ lw,
                                             const float* __restrict__ lb,
                                             float* __restrict__ out) {
  int b = blockIdx.x;
  int c = threadIdx.x;   // 0..127 output channel
  __shared__ float xs[NLAT];
  xs[c] = x[b*NLAT + c];
  __syncthreads();
  double a0=0, a1=0, a2=0, a3=0;
  for (int l = 0; l < NLAT; ++l) {
    double xv = (double)xs[l];
    float4 wv = *reinterpret_cast<const float4*>(lw + (size_t)l*512 + c*4);
    a0 += xv*(double)wv.x; a1 += xv*(double)wv.y;
    a2 += xv*(double)wv.z; a3 += xv*(double)wv.w;
  }
  float4 bv = *reinterpret_cast<const float4*>(lb + c*4);
  float4 o;
  o.x = (float)(a0 + (double)bv.x);
  o.y = (float)(a1 + (double)bv.y);
  o.z = (float)(a2 + (double)bv.z);
  o.w = (float)(a3 + (double)bv.w);
  *reinterpret_cast<float4*>(out + (size_t)b*512 + c*4) = o;
}

// ------------- k_kmat : exact band-limited 2x upsample matrices, all four sizes -------------
// K[m][j] = (1/n)[1 + 2*sum_{k=1}^{n/2-1} cos(pi k (m-2j)/n) + 2*cos(pi m/2)*(-1)^j]
// n=4 @0 (8x4), n=8 @32 (16x8), n=16 @160 (32x16), n=32 @672 (64x32). 2720 doubles total.
__global__ __launch_bounds__(256) void k_kmat(double* __restrict__ km) {
  __shared__ double ctab[64];
  int tid = threadIdx.x;
  const int ns[4]   = {4, 8, 16, 32};
  const int offs[4] = {0, 32, 160, 672};
  for (int si = 0; si < 4; ++si) {
    int n = ns[si];
    for (int d = tid; d < 2*n; d += 256) ctab[d] = cos(PI_D*(double)d/(double)n);
    __syncthreads();
    int tot = 2*n*n;
    for (int i = tid; i < tot; i += 256) {
      int m = i / n, j = i - (i/n)*n;
      int dm = m - 2*j;
      double s = 1.0;
      for (int k = 1; k <= n/2 - 1; ++k) s += 2.0*ctab[(k*dm) & (2*n-1)];
      double cm2 = (m & 1) ? 0.0 : ((m & 2) ? -1.0 : 1.0);
      s += 2.0*cm2*((j & 1) ? -1.0 : 1.0);
      km[offs[si] + m*n + j] = s/(double)n;
    }
    __syncthreads();
  }
}

// ------------- k_ups<NIN> : (B,128,NIN) -> (B,128,2NIN), one thread per output elem -------------
template<int NIN>
__global__ __launch_bounds__(256) void k_ups(const float* __restrict__ in,
                                             const double* __restrict__ K,
                                             float* __restrict__ out) {
  constexpr int M = 2*NIN;
  int idx = blockIdx.x*256 + threadIdx.x;        // = bc*M + m
  int m  = idx % M;
  int bc = idx / M;                              // b*128 + c
  const float*  xp = in + (size_t)bc*NIN;
  const double* Kr = K + m*NIN;
  double a = 0.0;
  #pragma unroll
  for (int j = 0; j < NIN; ++j) a += Kr[j]*(double)xp[j];
  out[(size_t)bc*M + m] = (float)a;
}

// ------------- k_conv<T,OCTOT,LEAKY> : conv3 'same', in (B,128,T) -> (B,OCTOT,T) -------------
// Block = (b, group of 256/T output channels). u tile in LDS (stride T+1 -> stride-1 lane
// reads, 2-way aliasing = free), weights in LDS at stride 385 (385%32==1).
template<int T, int OCTOT, bool LEAKY>
__global__ __launch_bounds__(256) void k_conv(const float* __restrict__ in,
                                              const float* __restrict__ w,
                                              const float* __restrict__ bias,
                                              float* __restrict__ out) {
  constexpr int OCB = 256/T;
  int b = blockIdx.x, g = blockIdx.y;
  int o0 = g*OCB;
  int tid = threadIdx.x;
  __shared__ float u[NCUP*(T+1)];
  __shared__ float wl[OCB*385];
  for (int i = tid; i < NCUP*T; i += 256) {
    int c = i / T, t2 = i - (i/T)*T;
    u[c*(T+1)+t2] = in[(size_t)b*NCUP*T + i];
  }
  for (int i = tid; i < OCB*384; i += 256) {
    int oi = i/384, r = i - oi*384;
    wl[oi*385+r] = w[(size_t)(o0+oi)*384 + r];
  }
  __syncthreads();
  int ol = tid / T, t = tid - (tid/T)*T;
  double a0 = 0.0, a1 = 0.0;
  const float* wr = wl + ol*385;
  for (int c = 0; c < NCUP; ++c) {
    int base = c*(T+1)+t;
    float xm = (t > 0)   ? u[base-1] : 0.f;
    float xc = u[base];
    float xp = (t < T-1) ? u[base+1] : 0.f;
    a0 += (double)wr[c*3+0]*(double)xm + (double)wr[c*3+1]*(double)xc;
    a1 += (double)wr[c*3+2]*(double)xp;
  }
  float v = (float)(a0 + a1 + (double)bias[o0+ol]);
  if (LEAKY) v = (v > 0.f) ? v : 0.2f*v;
  out[(size_t)b*OCTOT*T + (size_t)(o0+ol)*T + t] = v;
}

// ------------- k_dc : DC (sum) of each 512-sample noise window -------------
__global__ __launch_bounds__(64) void k_dc(const float* __restrict__ noise, float* __restrict__ dc) {
  int f = blockIdx.x, b = blockIdx.y;
  int lane = threadIdx.x;
  const float* p = noise + ((size_t)b*NFRM + f)*512;
  double a = 0.0;
  for (int i = lane; i < 512; i += 64) a += (double)p[i];
  for (int off = 32; off > 0; off >>= 1) a += __shfl_down(a, off);
  if (lane == 0) dc[b*NFRM + f] = (float)a;
}

// ------------- k_norm : instance norm, one wave per (b,channel) -------------
__global__ __launch_bounds__(64) void k_norm(const float* __restrict__ hfin,
                                             float* __restrict__ hnorm) {
  int bc = blockIdx.x;          // b*64 + c
  int lane = threadIdx.x;       // t
  const float* p = hfin + (size_t)bc*NMID;
  float v = p[lane];
  double s = (double)v;
  for (int off = 32; off > 0; off >>= 1) s += __shfl_down(s, off);
  double m = __shfl(s, 0) * (1.0/NMID);
  double d = (double)v - m;
  double s2 = d*d;
  for (int off = 32; off > 0; off >>= 1) s2 += __shfl_down(s2, off);
  double var = __shfl(s2, 0) * (1.0/NMID);
  float sc = (float)(1.0 / sqrt(var + 1e-5));
  hnorm[(size_t)bc*NMID + lane] = (float)d * sc;
}

// ------------- k_mm1 : t1[z] = leaky(W1[z] @ hnorm + b1[z]), z=0:h-chain z=1:t-chain -------------
__global__ __launch_bounds__(256) void k_mm1(const float* __restrict__ hnorm,
    const float* __restrict__ hw1, const float* __restrict__ hb1,
    const float* __restrict__ tw1, const float* __restrict__ tb1,
    float* __restrict__ t1buf) {
  int b = blockIdx.y, z = blockIdx.z;
  int o = blockIdx.x*4 + (threadIdx.x >> 6);     // wave-uniform -> weight loads are scalar
  int t = threadIdx.x & 63;
  const float* W = (z ? tw1 : hw1) + o*NMID;
  float bv = (z ? tb1 : hb1)[o];
  const float* X = hnorm + (size_t)b*4096 + t;
  double a0 = 0.0, a1 = 0.0;
  for (int c = 0; c < NMID; c += 2) {
    a0 += (double)W[c]   * (double)X[(size_t)c*64];
    a1 += (double)W[c+1] * (double)X[(size_t)(c+1)*64];
  }
  float v = (float)(a0 + a1 + (double)bv);
  v = (v > 0.f) ? v : 0.2f*v;
  t1buf[((size_t)b*2 + z)*4096 + o*64 + t] = v;
}

// ------------- k_mm2 : hh = hw2@t1h + hb2 (z=0); nb = tw2@t1t + tb2 (z=1) -------------
__global__ __launch_bounds__(256) void k_mm2(const float* __restrict__ t1buf,
    const float* __restrict__ hw2, const float* __restrict__ hb2,
    const float* __restrict__ tw2, const float* __restrict__ tb2,
    float* __restrict__ hh, float* __restrict__ nbuf) {
  int b = blockIdx.y, z = blockIdx.z;
  int o = blockIdx.x*4 + (threadIdx.x >> 6);
  int t = threadIdx.x & 63;
  const float* W = (z ? tw2 : hw2) + o*NMID;
  float bv = (z ? tb2 : hb2)[o];
  const float* X = t1buf + ((size_t)b*2 + z)*4096 + t;
  double a0 = 0.0, a1 = 0.0;
  for (int c = 0; c < NMID; c += 2) {
    a0 += (double)W[c]   * (double)X[(size_t)c*64];
    a1 += (double)W[c+1] * (double)X[(size_t)(c+1)*64];
  }
  float v = (float)(a0 + a1 + (double)bv);
  float* out = z ? nbuf : hh;
  out[(size_t)b*4096 + o*64 + t] = v;
}

// ------------- k_af : amp/freq heads fused -------------
__global__ __launch_bounds__(256) void k_af(const float* __restrict__ hh,
    const float* __restrict__ amp_w, const float* __restrict__ amp_b,
    const float* __restrict__ freq_w, const float* __restrict__ freq_b,
    float* __restrict__ ampg, float* __restrict__ freqg) {
  int b = blockIdx.y;
  int o = blockIdx.x*4 + (threadIdx.x >> 6);     // 0..127
  int t = threadIdx.x & 63;
  const float* X = hh + (size_t)b*4096 + t;
  const float* wa = amp_w + o*NMID;
  const float* wf = freq_w + o*NMID;
  double za = (double)amp_b[o], zf = (double)freq_b[o];
  for (int c = 0; c < NMID; ++c) {
    double hv = (double)X[(size_t)c*64];
    za += (double)wa[c]*hv;
    zf += (double)wf[c]*hv;
  }
  ampg[(size_t)b*8192 + o*64 + t] = fabsf((float)za);
  double sg = 1.0 / (1.0 + exp(-zf));
  freqg[(size_t)b*8192 + o*64 + t] = (float)(LOWEST_D + sg*sg*(1.0 - LOWEST_D));
}

// ------------- k_ncon : per-frame noise constant (DC-only filter) -------------
__global__ __launch_bounds__(64) void k_ncon(const float* __restrict__ nbuf,
    const float* __restrict__ nm_w1, const float* __restrict__ nm_b1,
    const float* __restrict__ nm_w2, const float* __restrict__ nm_b2,
    const float* __restrict__ dc, float* __restrict__ ncon) {
  int b = blockIdx.x;
  int f = threadIdx.x;            // frame
  __shared__ double veff[NMID];
  double a = 0.0;                 // veff[f] = sum_c nm_w2[0,c]*nm_w1[c,f]
  for (int c = 0; c < NCUP; ++c) a += (double)nm_w2[c] * (double)nm_w1[c*NMID + f];
  veff[f] = a;
  double beff = (double)nm_b2[0];
  for (int c = 0; c < NCUP; ++c) beff += (double)nm_w2[c] * (double)nm_b1[c];
  __syncthreads();
  double s0 = beff;
  const float* nbp = nbuf + (size_t)b*4096 + f;
  for (int m = 0; m < NMID; ++m) s0 += veff[m] * (double)nbp[(size_t)m*64];
  ncon[b*NFRM + f] = (float)((double)dc[b*NFRM + f] * s0 * (1.0/512.0));
}

// ------------- k_prefix : per-(b,osc) segment-start phases in REVOLUTION units (fp64) -------------
// Segments of the 64->16384 linterp: seg0 = [0,128) const f[0]; seg j(1..63) = [256j-128,256j+128)
// linear f[j-1]->f[j] with w = 1/512 + i/256; seg64 = [16256,16384) const f[63].
// rev(phase)/2pi: seg sum = 64*f0 ; 64*(f[j-1]+f[j]).
__global__ __launch_bounds__(256) void k_prefix(const float* __restrict__ freqg,
                                                const float* __restrict__ ampg,
                                                double* __restrict__ P0g,
                                                float4* __restrict__ segT) {
  int idx = blockIdx.x*blockDim.x + threadIdx.x;   // 0..4095 = b*128+osc
  int b = idx >> 7, osc = idx & 127;
  const float* F = freqg + (size_t)b*NOSC_*NFRM + osc*NFRM;
  const float* A = ampg  + (size_t)b*NOSC_*NFRM + osc*NFRM;
  P0g[0*4096 + idx] = 0.0;
  segT[0*4096 + idx] = make_float4(F[0], 0.f, A[0], 0.f);
  double p = 64.0 * (double)F[0];
  for (int j = 1; j <= 63; ++j) {
    P0g[j*4096 + idx] = p;
    float fl = F[j-1], fh = F[j], al = A[j-1], ah = A[j];
    segT[j*4096 + idx] = make_float4(fl, fh - fl, al, ah - al);
    p += 64.0 * ((double)fl + (double)fh);
  }
  P0g[64*4096 + idx] = p;
  segT[64*4096 + idx] = make_float4(F[63], 0.f, A[63], 0.f);
}

// ------------- k_harm : block = (q,b): 256 samples, 128 oscillators -------------
// rev(s) = P0r + 0.5*[(r+1)*f_lo + ((r+1)*w0 + r(r+1)/512)*df], fract -> v_sin_f32(revs).
__global__ __launch_bounds__(256) void k_harm(const double* __restrict__ P0g,
                                              const float4* __restrict__ segT,
                                              const float* __restrict__ nc,
                                              float* __restrict__ outp) {
  int q = blockIdx.x;        // 0..63
  int b = blockIdx.y;
  int tid = threadIdx.x;
  __shared__ double P0s[256];     // [half][osc]
  __shared__ float4 segs[256];
  int half = tid >> 7;
  int osc  = tid & 127;
  {
    int j = q + half;
    P0s[tid]  = P0g[(size_t)j*4096 + b*128 + osc];
    segs[tid] = segT[(size_t)j*4096 + b*128 + osc];
  }
  __syncthreads();

  int j = q + half;
  int s = q*256 + tid;
  int r = (j == 0) ? s : (s - (256*j - 128));
  float w0 = (j == 0 || j == 64) ? 0.f : (1.f/512.f);
  double rp = (double)(r + 1);
  double c1 = rp * 0.5;
  double c2 = (rp*(double)w0 + (double)r*rp*(1.0/512.0)) * 0.5;
  float wr = w0 + (float)r*(1.f/256.f);

  const double* P0p = P0s + half*128;
  const float4* sp  = segs + half*128;
  float acc = 0.f;
  #pragma unroll 4
  for (int o = 0; o < 128; ++o) {
    float4 sg = sp[o];                 // {f_lo, df, a_lo, da} -- wave-uniform LDS broadcast
    double rev = P0p[o] + c1*(double)sg.x + c2*(double)sg.y;
    rev -= floor(rev);                 // fractional revolutions
    float sv = __builtin_amdgcn_sinf((float)rev);   // v_sin_f32: sin(2*pi*x)
    float am = sg.z + sg.w*wr;
    acc = fmaf(sv, am, acc);
  }
  float ns = nc[b*NFRM + q] + ((q > 0) ? nc[b*NFRM + q - 1] : 0.f);
  outp[(size_t)b*NSMP + s] = acc + ns;
}

// ---------------------------------------------------------------------------
extern "C" void kernel_launch(void* const* d_in, const int* in_sizes, int n_in,
                              void* d_out, int out_size, void* d_ws, size_t ws_size,
                              hipStream_t stream) {
  (void)in_sizes; (void)n_in; (void)out_size; (void)ws_size;
  const float* x      = (const float*)d_in[0];
  const float* lin_w  = (const float*)d_in[1];
  const float* lin_b  = (const float*)d_in[2];
  const float* up_w0  = (const float*)d_in[3];
  const float* up_b0  = (const float*)d_in[4];
  const float* up_w1  = (const float*)d_in[5];
  const float* up_b1  = (const float*)d_in[6];
  const float* up_w2  = (const float*)d_in[7];
  const float* up_b2  = (const float*)d_in[8];
  const float* up_w3  = (const float*)d_in[9];
  const float* up_b3  = (const float*)d_in[10];
  const float* fin_w  = (const float*)d_in[11];
  const float* fin_b  = (const float*)d_in[12];
  const float* hw1    = (const float*)d_in[13];
  const float* hb1    = (const float*)d_in[14];
  const float* hw2    = (const float*)d_in[15];
  const float* hb2    = (const float*)d_in[16];
  const float* tw1    = (const float*)d_in[17];
  const float* tb1    = (const float*)d_in[18];
  const float* tw2    = (const float*)d_in[19];
  const float* tb2    = (const float*)d_in[20];
  const float* amp_w  = (const float*)d_in[21];
  const float* amp_b  = (const float*)d_in[22];
  const float* freq_w = (const float*)d_in[23];
  const float* freq_b = (const float*)d_in[24];
  const float* nm_w1  = (const float*)d_in[25];
  const float* nm_b1  = (const float*)d_in[26];
  const float* nm_w2  = (const float*)d_in[27];
  const float* nm_b2  = (const float*)d_in[28];
  const float* noise  = (const float*)d_in[29];

  float* ws = (float*)d_ws;
  float* buf0  = ws;                       // 262144 floats
  float* buf1  = ws + 262144;              // 262144
  float* hfin  = ws + 524288;              // 131072 (dead after k_norm -> reused for nb)
  float* ampg  = ws + 655360;              // 262144 (first 5440 floats host Kmat until k_af)
  float* freqg = ws + 917504;              // 262144
  float* dc    = ws + 1179648;             // 2048
  float* ncon  = ws + 1181696;             // 2048
  double* P0g  = (double*)(ws + 1183744);  // 65*4096 doubles
  float4* segT = (float4*)(ws + 1716224);  // 65*4096 float4

  // Kmat lives in ampg's region: ups stages (launches 3-10) finish before k_af writes ampg.
  double* Kmat = (double*)(ws + 655360);   // 2720 doubles

  // post-upconv reuse (regions dead by the time they're written):
  float* hnorm = buf1;                     // buf1 free after last ups consumer
  float* hh    = buf1 + 131072;
  float* t1buf = buf0;                     // buf0 free after fin conv
  float* nbuf  = hfin;                     // hfin free after k_norm

  k_lin<<<NB, 128, 0, stream>>>(x, lin_w, lin_b, buf0);
  k_kmat<<<1, 256, 0, stream>>>(Kmat);
  k_ups< 4><<< 128, 256, 0, stream>>>(buf0, Kmat + 0,   buf1);   // (B,128,8)
  k_conv< 8, 128, true ><<<dim3(NB, 4), 256, 0, stream>>>(buf1, up_w0, up_b0, buf0);
  k_ups< 8><<< 256, 256, 0, stream>>>(buf0, Kmat + 32,  buf1);   // (B,128,16)
  k_conv<16, 128, true ><<<dim3(NB, 8), 256, 0, stream>>>(buf1, up_w1, up_b1, buf0);
  k_ups<16><<< 512, 256, 0, stream>>>(buf0, Kmat + 160, buf1);   // (B,128,32)
  k_conv<32, 128, true ><<<dim3(NB,16), 256, 0, stream>>>(buf1, up_w2, up_b2, buf0);
  k_ups<32><<<1024, 256, 0, stream>>>(buf0, Kmat + 672, buf1);   // (B,128,64)
  k_conv<64, 128, true ><<<dim3(NB,32), 256, 0, stream>>>(buf1, up_w3, up_b3, buf0);
  k_conv<64,  64, false><<<dim3(NB,16), 256, 0, stream>>>(buf0, fin_w, fin_b, hfin);
  k_dc<<<dim3(NFRM, NB), 64, 0, stream>>>(noise, dc);
  k_norm<<<NB*NMID, 64, 0, stream>>>(hfin, hnorm);
  k_mm1<<<dim3(16, NB, 2), 256, 0, stream>>>(hnorm, hw1, hb1, tw1, tb1, t1buf);
  k_mm2<<<dim3(16, NB, 2), 256, 0, stream>>>(t1buf, hw2, hb2, tw2, tb2, hh, nbuf);
  k_af<<<dim3(32, NB), 256, 0, stream>>>(hh, amp_w, amp_b, freq_w, freq_b, ampg, freqg);
  k_ncon<<<NB, 64, 0, stream>>>(nbuf, nm_w1, nm_b1, nm_w2, nm_b2, dc, ncon);
  k_prefix<<<16, 256, 0, stream>>>(freqg, ampg, P0g, segT);
  k_harm<<<dim3(64, NB), 256, 0, stream>>>(P0g, segT, ncon, (float*)d_out);
}